// Round 6
// baseline (53.542 us; speedup 1.0000x reference)
//
#include <hip/hip_runtime.h>
#include <math.h>

// query:  [B, D]   f32
// values: [B, T, D] f32
// out: context [B, D] ++ weights [B, T], f32, concatenated flat.
#define B_ 32
#define T_ 8192
#define D_ 256
#define TTILE 256            // t-rows per block
#define NT (T_ / TTILE)      // 32 tiles per batch
#define NPART (B_ * NT)      // 1024 blocks = 4/CU, one uniform wave of blocks
#define NROW (TTILE / 8)     // 32 rows per stream
#define RESC_THR 8.0f        // defer-max threshold (exp bounded by e^8)

// native 4-float vector (works with __builtin_nontemporal_load, unlike
// HIP's float4 which is a class type)
typedef float f4 __attribute__((ext_vector_type(4)));

// ---------------------------------------------------------------------------
// Pass 1: stream values ONCE. 1024 blocks x 256 threads, 4 blocks/CU
// co-resident (launch_bounds caps VGPR at 128) -> no occupancy tail.
// Block = (b, tile of 256 rows). 4 waves x 2 half-waves = 8 row-streams;
// each half-wave (32 lanes x 8 floats) owns one row per iteration.
// Depth-2 prefetch, peeled tail, non-temporal v loads (stream-once data).
// Online softmax with deferred rescale (anchor m, trigger at p > m+8).
// ---------------------------------------------------------------------------
__global__ __launch_bounds__(256, 4) void attn_pass1(
    const float* __restrict__ q,
    const float* __restrict__ v,
    float* __restrict__ scores_out,   // weights region of d_out (raw scores)
    float* __restrict__ part_m,
    float* __restrict__ part_l,
    float* __restrict__ part_o)
{
    const int blk  = blockIdx.x;
    const int b    = blk >> 5;        // / NT
    const int tile = blk & (NT - 1);  // % NT
    const int t0   = tile * TTILE;
    const int tid  = threadIdx.x;
    const int wave = tid >> 6;
    const int lane = tid & 63;
    const int half = lane >> 5;       // 0 or 1
    const int hl   = lane & 31;       // lane within half-wave
    const int sid  = wave * 2 + half; // stream id, 0..7

    __shared__ float s_sh[TTILE];
    __shared__ float sm[8], sl[8];
    __shared__ float so[8][D_];

    // q slice: 8 consecutive floats per lane (32 lanes cover D=256)
    const f4* q4p = reinterpret_cast<const f4*>(q + b * D_);
    const f4 q0 = q4p[hl * 2];
    const f4 q1 = q4p[hl * 2 + 1];

    const float* vbase = v + ((size_t)b * T_ + t0 + sid) * D_;

    float m = -INFINITY;
    float l = 0.0f;
    f4 o0 = (f4)(0.0f);
    f4 o1 = (f4)(0.0f);

    // row loader: iteration i covers row t0 + i*8 + sid (non-temporal:
    // every byte of v is consumed exactly once -> don't pollute L2/L3)
    auto ld = [&](int i, f4& x0, f4& x1) {
        const f4* p = reinterpret_cast<const f4*>(vbase + (size_t)i * 8 * D_);
        x0 = __builtin_nontemporal_load(&p[hl * 2]);
        x1 = __builtin_nontemporal_load(&p[hl * 2 + 1]);
    };

    // score + online-softmax update for one row
    auto proc = [&](int i, const f4& a0, const f4& a1) {
        float p = fmaf(q0.x, a0.x, fmaf(q0.y, a0.y,
                  fmaf(q0.z, a0.z, fmaf(q0.w, a0.w,
                  fmaf(q1.x, a1.x, fmaf(q1.y, a1.y,
                  fmaf(q1.z, a1.z, q1.w * a1.w)))))));

        // 5-step butterfly within the 32-lane half
        #pragma unroll
        for (int off = 16; off >= 1; off >>= 1)
            p += __shfl_xor(p, off, 64);

        if (hl == 0) s_sh[i * 8 + sid] = p;   // raw score -> LDS

        // deferred-rescale online softmax (anchor m)
        if (__any(p > m + RESC_THR)) {
            const float mnew = fmaxf(m, p);
            const float sc   = __expf(m - mnew);   // exp(-inf)=0 first time
            l  *= sc;
            o0 *= sc;
            o1 *= sc;
            m = mnew;
        }
        const float w = __expf(p - m);    // bounded by e^RESC_THR
        l += w;
        o0 = fmaf(w, a0.x, o0.x), o0;     // (placeholder no-op removed below)
    };
    (void)0;

    // NOTE: vector fma via element ops — keep it explicit for codegen clarity
    auto procx = [&](int i, const f4& a0, const f4& a1) {
        float p = fmaf(q0.x, a0.x, fmaf(q0.y, a0.y,
                  fmaf(q0.z, a0.z, fmaf(q0.w, a0.w,
                  fmaf(q1.x, a1.x, fmaf(q1.y, a1.y,
                  fmaf(q1.z, a1.z, q1.w * a1.w)))))));

        #pragma unroll
        for (int off = 16; off >= 1; off >>= 1)
            p += __shfl_xor(p, off, 64);

        if (hl == 0) s_sh[i * 8 + sid] = p;

        if (__any(p > m + RESC_THR)) {
            const float mnew = fmaxf(m, p);
            const float sc   = __expf(m - mnew);
            l  *= sc;
            o0 *= sc;
            o1 *= sc;
            m = mnew;
        }
        const float w = __expf(p - m);
        l += w;
        o0.x = fmaf(w, a0.x, o0.x); o0.y = fmaf(w, a0.y, o0.y);
        o0.z = fmaf(w, a0.z, o0.z); o0.w = fmaf(w, a0.w, o0.w);
        o1.x = fmaf(w, a1.x, o1.x); o1.y = fmaf(w, a1.y, o1.y);
        o1.z = fmaf(w, a1.z, o1.z); o1.w = fmaf(w, a1.w, o1.w);
    };

    // ---- depth-2 pairwise prefetch over NROW rows, peeled tail ----
    f4 A0, A1, B0, B1;
    ld(0, A0, A1);
    ld(1, B0, B1);

    #pragma unroll 3
    for (int i = 0; i < NROW - 2; i += 2) {
        f4 C0, C1, E0, E1;
        ld(i + 2, C0, C1);
        ld(i + 3, E0, E1);
        procx(i,     A0, A1);
        procx(i + 1, B0, B1);
        A0 = C0; A1 = C1; B0 = E0; B1 = E1;
    }
    procx(NROW - 2, A0, A1);
    procx(NROW - 1, B0, B1);

    // stash per-stream state
    if (hl == 0) { sm[sid] = m; sl[sid] = l; }
    f4* sop = reinterpret_cast<f4*>(&so[sid][hl * 8]);
    sop[0] = o0;
    sop[1] = o1;
    __syncthreads();

    // combine the 8 streams (every thread recomputes the cheap scalars)
    float M = sm[0];
    #pragma unroll
    for (int s = 1; s < 8; ++s) M = fmaxf(M, sm[s]);

    float es[8];
    #pragma unroll
    for (int s = 0; s < 8; ++s) es[s] = __expf(sm[s] - M);

    float oc = 0.0f;
    #pragma unroll
    for (int s = 0; s < 8; ++s) oc = fmaf(so[s][tid], es[s], oc);
    part_o[(size_t)blk * D_ + tid] = oc;

    if (tid == 0) {
        float L = 0.0f;
        #pragma unroll
        for (int s = 0; s < 8; ++s) L = fmaf(sl[s], es[s], L);
        part_m[blk] = M;
        part_l[blk] = L;
    }

    // coalesced raw-score store
    scores_out[(size_t)b * T_ + t0 + tid] = s_sh[tid];
}

// ---------------------------------------------------------------------------
// Pass 2 (fused): one 1024-thread block per batch b.
//   lanes 0-31:  butterfly-reduce NT=32 partial (m,l) -> M, invL
//   4 groups:    8 partials each -> ctx (4x parallel reduction)
//   all 1024:    normalize 8192 raw scores (2 x float4 per thread)
// ---------------------------------------------------------------------------
__global__ __launch_bounds__(1024) void attn_pass2(
    const float* __restrict__ part_m,
    const float* __restrict__ part_l,
    const float* __restrict__ part_o,
    float* __restrict__ ctx,          // [B, D]
    float* __restrict__ wts)          // [B, T] raw scores in, weights out
{
    const int b    = blockIdx.x;
    const int tid  = threadIdx.x;
    const int base = b * NT;          // NT = 32

    __shared__ float sscale[NT];
    __shared__ float sML[2];
    __shared__ float octx[4][D_];

    // ---- lanes 0-31 of wave 0: M and invL via butterflies ----
    if (tid < NT) {
        const float mv = part_m[base + tid];
        float M = mv;
        #pragma unroll
        for (int off = 16; off >= 1; off >>= 1)
            M = fmaxf(M, __shfl_xor(M, off, 64));

        const float sc = __expf(mv - M);
        sscale[tid] = sc;

        float lv = part_l[base + tid] * sc;
        #pragma unroll
        for (int off = 16; off >= 1; off >>= 1)
            lv += __shfl_xor(lv, off, 64);

        if (tid == 0) { sML[0] = M; sML[1] = 1.0f / lv; }
    }
    __syncthreads();
    const float M    = sML[0];
    const float invL = sML[1];

    // ---- ctx: 4 groups x 8 partials, coalesced over d ----
    const int grp = tid >> 8;   // 0..3
    const int d   = tid & 255;
    float o = 0.0f;
    #pragma unroll
    for (int p = 0; p < 8; ++p) {
        const int pi = grp * 8 + p;
        o = fmaf(part_o[(size_t)(base + pi) * D_ + d], sscale[pi], o);
    }
    octx[grp][d] = o;
    __syncthreads();
    if (tid < D_)
        ctx[b * D_ + tid] =
            (octx[0][tid] + octx[1][tid] + octx[2][tid] + octx[3][tid]) * invL;

    // ---- normalize weights: 1024 threads x float4 x 2 ----
    f4* wp = reinterpret_cast<f4*>(wts + (size_t)b * T_);
    #pragma unroll
    for (int it = 0; it < 2; ++it) {
        f4 x = wp[it * 1024 + tid];
        x.x = __expf(x.x - M) * invL;
        x.y = __expf(x.y - M) * invL;
        x.z = __expf(x.z - M) * invL;
        x.w = __expf(x.w - M) * invL;
        wp[it * 1024 + tid] = x;
    }
}

extern "C" void kernel_launch(void* const* d_in, const int* in_sizes, int n_in,
                              void* d_out, int out_size, void* d_ws, size_t ws_size,
                              hipStream_t stream)
{
    const float* q = (const float*)d_in[0];   // [B, D]
    const float* v = (const float*)d_in[1];   // [B, T, D]

    float* out = (float*)d_out;
    float* ctx = out;             // [B, D]
    float* wts = out + B_ * D_;   // [B, T]

    // workspace: part_m[NPART] | part_l[NPART] | part_o[NPART*D_]
    float* part_m = (float*)d_ws;
    float* part_l = part_m + NPART;
    float* part_o = part_l + NPART;

    attn_pass1<<<NPART, 256, 0, stream>>>(q, v, wts, part_m, part_l, part_o);
    attn_pass2<<<B_, 1024, 0, stream>>>(part_m, part_l, part_o, ctx, wts);
}

// Round 7
// 49.475 us; speedup vs baseline: 1.0822x; 1.0822x over previous
//
#include <hip/hip_runtime.h>
#include <math.h>

// query:  [B, D]   f32
// values: [B, T, D] f32
// out: context [B, D] ++ weights [B, T], f32, concatenated flat.
#define B_ 32
#define T_ 8192
#define D_ 256
#define TTILE 128            // t-rows per block
#define NT (T_ / TTILE)      // 64 tiles per batch
#define NPART (B_ * NT)      // 2048 blocks = 8/CU, ALL co-resident at 64 VGPR
#define NROWW (TTILE / 4)    // 32 rows per wave-stream
#define RESC_THR 8.0f        // defer-max threshold (exp bounded by e^8)

typedef float f4 __attribute__((ext_vector_type(4)));

// ---------------------------------------------------------------------------
// Pass 1: stream values ONCE. 2048 blocks x 256 threads.
// __launch_bounds__(256, 8): 8 waves/SIMD -> VGPR capped at 64 -> 8 blocks/CU
// -> all 2048 blocks co-resident (32 waves/CU, hardware max TLP), zero tail.
//
// One row per FULL wave per iteration: 64 lanes x float4 = 1 KB row.
//   row = t0 + i*4 + wave, i = 0..31. Depth-2 pairwise prefetch, peeled tail.
// Online softmax with deferred rescale (anchor m, trigger at p > m+8).
// Per-thread state is small by design: q(4) + o(4) + 4 row buffers(16).
// ---------------------------------------------------------------------------
__global__ __launch_bounds__(256, 8) void attn_pass1(
    const float* __restrict__ q,
    const float* __restrict__ v,
    float* __restrict__ scores_out,   // weights region of d_out (raw scores)
    float* __restrict__ part_m,
    float* __restrict__ part_l,
    float* __restrict__ part_o)
{
    const int blk  = blockIdx.x;
    const int b    = blk >> 6;        // / NT
    const int tile = blk & (NT - 1);  // % NT
    const int t0   = tile * TTILE;
    const int tid  = threadIdx.x;
    const int wave = tid >> 6;
    const int lane = tid & 63;

    __shared__ float s_sh[TTILE];
    __shared__ float sm[4], sl[4];
    __shared__ float so[4][D_];

    // q slice: 4 consecutive floats per lane (64 lanes cover D=256)
    const f4 q4 = reinterpret_cast<const f4*>(q + b * D_)[lane];

    // wave's row stream starts at row t0 + wave
    const float* vbase = v + ((size_t)b * T_ + t0 + wave) * D_;

    float m = -INFINITY;
    float l = 0.0f;
    f4 o = (f4)(0.0f);

    // row loader: iteration i covers row t0 + i*4 + wave (1 KB, coalesced)
    auto ld = [&](int i, f4& x) {
        x = reinterpret_cast<const f4*>(vbase + (size_t)i * 4 * D_)[lane];
    };

    // score + online-softmax update for one row
    auto proc = [&](int i, const f4& a) {
        float p = fmaf(q4.x, a.x, fmaf(q4.y, a.y,
                  fmaf(q4.z, a.z, q4.w * a.w)));

        // 6-step butterfly across the full 64-lane wave
        #pragma unroll
        for (int off = 32; off >= 1; off >>= 1)
            p += __shfl_xor(p, off, 64);

        if (lane == 0) s_sh[i * 4 + wave] = p;   // raw score -> LDS

        // deferred-rescale online softmax (anchor m)
        if (__any(p > m + RESC_THR)) {
            const float mnew = fmaxf(m, p);
            const float sc   = __expf(m - mnew);   // exp(-inf)=0 first time
            l *= sc;
            o *= sc;
            m = mnew;
        }
        const float w = __expf(p - m);    // bounded by e^RESC_THR
        l += w;
        o.x = fmaf(w, a.x, o.x); o.y = fmaf(w, a.y, o.y);
        o.z = fmaf(w, a.z, o.z); o.w = fmaf(w, a.w, o.w);
    };

    // ---- depth-2 pairwise prefetch over NROWW rows, peeled tail ----
    f4 A, Bv;
    ld(0, A);
    ld(1, Bv);

    #pragma unroll 5
    for (int i = 0; i < NROWW - 2; i += 2) {
        f4 C, E;
        ld(i + 2, C);
        ld(i + 3, E);
        proc(i,     A);
        proc(i + 1, Bv);
        A = C; Bv = E;
    }
    proc(NROWW - 2, A);
    proc(NROWW - 1, Bv);

    // stash per-wave-stream state
    if (lane == 0) { sm[wave] = m; sl[wave] = l; }
    reinterpret_cast<f4*>(&so[wave][0])[lane] = o;
    __syncthreads();

    // combine the 4 streams (every thread recomputes the cheap scalars)
    const float M = fmaxf(fmaxf(sm[0], sm[1]), fmaxf(sm[2], sm[3]));
    const float e0 = __expf(sm[0] - M);
    const float e1 = __expf(sm[1] - M);
    const float e2 = __expf(sm[2] - M);
    const float e3 = __expf(sm[3] - M);

    const float oc = so[0][tid] * e0 + so[1][tid] * e1 +
                     so[2][tid] * e2 + so[3][tid] * e3;
    part_o[(size_t)blk * D_ + tid] = oc;

    if (tid == 0) {
        part_m[blk] = M;
        part_l[blk] = sl[0] * e0 + sl[1] * e1 + sl[2] * e2 + sl[3] * e3;
    }

    // coalesced raw-score store
    if (tid < TTILE)
        scores_out[(size_t)b * T_ + t0 + tid] = s_sh[tid];
}

// ---------------------------------------------------------------------------
// Pass 2 (fused): one 1024-thread block per batch b.  (round-3 proven)
//   wave 0:    butterfly-reduce NT=64 partial (m,l) -> M, invL
//   4 groups:  16 partials each -> ctx (4x parallel reduction)
//   all 1024:  normalize 8192 raw scores (2 x float4 per thread)
// ---------------------------------------------------------------------------
__global__ __launch_bounds__(1024) void attn_pass2(
    const float* __restrict__ part_m,
    const float* __restrict__ part_l,
    const float* __restrict__ part_o,
    float* __restrict__ ctx,          // [B, D]
    float* __restrict__ wts)          // [B, T] raw scores in, weights out
{
    const int b    = blockIdx.x;
    const int tid  = threadIdx.x;
    const int base = b * NT;          // NT = 64

    __shared__ float sscale[NT];
    __shared__ float sML[2];
    __shared__ float octx[4][D_];

    // ---- wave 0: M and invL via 64-lane butterflies ----
    if (tid < 64) {
        const float mv = part_m[base + tid];
        float M = mv;
        #pragma unroll
        for (int off = 32; off >= 1; off >>= 1)
            M = fmaxf(M, __shfl_xor(M, off, 64));

        const float sc = __expf(mv - M);
        sscale[tid] = sc;

        float lv = part_l[base + tid] * sc;
        #pragma unroll
        for (int off = 32; off >= 1; off >>= 1)
            lv += __shfl_xor(lv, off, 64);

        if (tid == 0) { sML[0] = M; sML[1] = 1.0f / lv; }
    }
    __syncthreads();
    const float M    = sML[0];
    const float invL = sML[1];

    // ---- ctx: 4 groups x 16 partials, coalesced over d ----
    const int grp = tid >> 8;   // 0..3
    const int d   = tid & 255;
    float o = 0.0f;
    #pragma unroll
    for (int p = 0; p < 16; ++p) {
        const int pi = grp * 16 + p;
        o = fmaf(part_o[(size_t)(base + pi) * D_ + d], sscale[pi], o);
    }
    octx[grp][d] = o;
    __syncthreads();
    if (tid < D_)
        ctx[b * D_ + tid] =
            (octx[0][tid] + octx[1][tid] + octx[2][tid] + octx[3][tid]) * invL;

    // ---- normalize weights: 1024 threads x float4 x 2 ----
    f4* wp = reinterpret_cast<f4*>(wts + (size_t)b * T_);
    #pragma unroll
    for (int it = 0; it < 2; ++it) {
        f4 x = wp[it * 1024 + tid];
        x.x = __expf(x.x - M) * invL;
        x.y = __expf(x.y - M) * invL;
        x.z = __expf(x.z - M) * invL;
        x.w = __expf(x.w - M) * invL;
        wp[it * 1024 + tid] = x;
    }
}

extern "C" void kernel_launch(void* const* d_in, const int* in_sizes, int n_in,
                              void* d_out, int out_size, void* d_ws, size_t ws_size,
                              hipStream_t stream)
{
    const float* q = (const float*)d_in[0];   // [B, D]
    const float* v = (const float*)d_in[1];   // [B, T, D]

    float* out = (float*)d_out;
    float* ctx = out;             // [B, D]
    float* wts = out + B_ * D_;   // [B, T]

    // workspace: part_m[NPART] | part_l[NPART] | part_o[NPART*D_]
    float* part_m = (float*)d_ws;
    float* part_l = part_m + NPART;
    float* part_o = part_l + NPART;

    attn_pass1<<<NPART, 256, 0, stream>>>(q, v, wts, part_m, part_l, part_o);
    attn_pass2<<<B_, 1024, 0, stream>>>(part_m, part_l, part_o, ctx, wts);
}

// Round 8
// 49.379 us; speedup vs baseline: 1.0843x; 1.0019x over previous
//
#include <hip/hip_runtime.h>
#include <math.h>

// query:  [B, D]   f32
// values: [B, T, D] f32
// out: context [B, D] ++ weights [B, T], f32, concatenated flat.
#define B_ 32
#define T_ 8192
#define D_ 256
#define TTILE 128            // t-rows per block
#define NT (T_ / TTILE)      // 64 tiles per batch
#define NPART (B_ * NT)      // 2048 blocks / partials
#define RESC_THR 8.0f        // defer-max threshold (exp bounded by e^8)

typedef float f4 __attribute__((ext_vector_type(4)));

// ---------------------------------------------------------------------------
// Pass 1 — EXACT round-3 structure (measured best: ~44 us, ~6.1 TB/s).
// Block = (b, tile of 128 rows). 4 waves x 2 half-waves = 8 row-streams.
// Each half-wave (32 lanes x 8 floats) owns one row per iteration.
// Depth-2 prefetch, peeled tail. Online softmax with deferred rescale.
// ---------------------------------------------------------------------------
__global__ __launch_bounds__(256) void attn_pass1(
    const float* __restrict__ q,
    const float* __restrict__ v,
    float* __restrict__ scores_out,   // weights region of d_out (raw scores)
    float* __restrict__ part_m,
    float* __restrict__ part_l,
    float* __restrict__ part_o)
{
    const int blk  = blockIdx.x;
    const int b    = blk >> 6;        // / NT
    const int tile = blk & (NT - 1);  // % NT
    const int t0   = tile * TTILE;
    const int tid  = threadIdx.x;
    const int wave = tid >> 6;
    const int lane = tid & 63;
    const int half = lane >> 5;       // 0 or 1
    const int hl   = lane & 31;       // lane within half-wave
    const int sid  = wave * 2 + half; // stream id, 0..7

    __shared__ float s_sh[TTILE];
    __shared__ float sm[8], sl[8];
    __shared__ float so[8][D_];

    // q slice: 8 consecutive floats per lane (32 lanes cover D=256)
    const float4* q4p = reinterpret_cast<const float4*>(q + b * D_);
    const float4 q0 = q4p[hl * 2];
    const float4 q1 = q4p[hl * 2 + 1];

    const float* vbase = v + ((size_t)b * T_ + t0 + sid) * D_;

    float  m = -INFINITY;
    float  l = 0.0f;
    float4 o0 = make_float4(0.f, 0.f, 0.f, 0.f);
    float4 o1 = make_float4(0.f, 0.f, 0.f, 0.f);

    // row loader: iteration i covers row t0 + i*8 + sid
    auto ld = [&](int i, float4& x0, float4& x1) {
        const float4* p =
            reinterpret_cast<const float4*>(vbase + (size_t)i * 8 * D_);
        x0 = p[hl * 2];
        x1 = p[hl * 2 + 1];
    };

    // score + online-softmax update for one row
    auto proc = [&](int i, const float4& a0, const float4& a1) {
        float p = fmaf(q0.x, a0.x, fmaf(q0.y, a0.y,
                  fmaf(q0.z, a0.z, fmaf(q0.w, a0.w,
                  fmaf(q1.x, a1.x, fmaf(q1.y, a1.y,
                  fmaf(q1.z, a1.z, q1.w * a1.w)))))));

        // 5-step butterfly within the 32-lane half
        #pragma unroll
        for (int off = 16; off >= 1; off >>= 1)
            p += __shfl_xor(p, off, 64);

        if (hl == 0) s_sh[i * 8 + sid] = p;   // raw score

        // deferred-rescale online softmax (anchor m)
        if (__any(p > m + RESC_THR)) {
            const float mnew = fmaxf(m, p);
            const float sc   = __expf(m - mnew);   // exp(-inf)=0 first time
            l    *= sc;
            o0.x *= sc; o0.y *= sc; o0.z *= sc; o0.w *= sc;
            o1.x *= sc; o1.y *= sc; o1.z *= sc; o1.w *= sc;
            m = mnew;
        }
        const float w = __expf(p - m);    // bounded by e^RESC_THR
        l += w;
        o0.x = fmaf(w, a0.x, o0.x); o0.y = fmaf(w, a0.y, o0.y);
        o0.z = fmaf(w, a0.z, o0.z); o0.w = fmaf(w, a0.w, o0.w);
        o1.x = fmaf(w, a1.x, o1.x); o1.y = fmaf(w, a1.y, o1.y);
        o1.z = fmaf(w, a1.z, o1.z); o1.w = fmaf(w, a1.w, o1.w);
    };

    float4 A0, A1, B0, B1;
    ld(0, A0, A1);
    ld(1, B0, B1);

    #pragma unroll
    for (int i = 0; i < 16; i += 2) {
        float4 C0, C1, E0, E1;
        if (i + 2 < 16) ld(i + 2, C0, C1);
        if (i + 3 < 16) ld(i + 3, E0, E1);
        proc(i,     A0, A1);
        proc(i + 1, B0, B1);
        if (i + 2 < 16) { A0 = C0; A1 = C1; }
        if (i + 3 < 16) { B0 = E0; B1 = E1; }
    }

    // stash per-stream state
    if (hl == 0) { sm[sid] = m; sl[sid] = l; }
    float4* sop = reinterpret_cast<float4*>(&so[sid][hl * 8]);
    sop[0] = o0;
    sop[1] = o1;
    __syncthreads();

    // combine the 8 streams (every thread recomputes the cheap scalars)
    float M = sm[0];
    #pragma unroll
    for (int s = 1; s < 8; ++s) M = fmaxf(M, sm[s]);

    float es[8];
    #pragma unroll
    for (int s = 0; s < 8; ++s) es[s] = __expf(sm[s] - M);

    float oc = 0.0f;
    #pragma unroll
    for (int s = 0; s < 8; ++s) oc = fmaf(so[s][tid], es[s], oc);
    part_o[(size_t)blk * D_ + tid] = oc;

    if (tid == 0) {
        float L = 0.0f;
        #pragma unroll
        for (int s = 0; s < 8; ++s) L = fmaf(sl[s], es[s], L);
        part_m[blk] = M;
        part_l[blk] = L;
    }

    // coalesced raw-score store
    if (tid < TTILE)
        scores_out[(size_t)b * T_ + t0 + tid] = s_sh[tid];
}

// ---------------------------------------------------------------------------
// Pass 2 (wide): 256 blocks x 256 threads, blk = b*8 + s.
//   Every block: wave-0 butterfly over the 64 (m,l) partials -> M, invL,
//                sscale[64] (512 B per batch, L2-hot after 8x reuse).
//   Every block: normalize weights slice s (1024 floats, f4).
//   Blocks s<2:  ctx d-split — s=0 covers d 0..127, s=1 covers d 128..255;
//                no cross-block combine (each d-column owned by one block).
// ---------------------------------------------------------------------------
__global__ __launch_bounds__(256) void attn_pass2(
    const float* __restrict__ part_m,
    const float* __restrict__ part_l,
    const float* __restrict__ part_o,
    float* __restrict__ ctx,          // [B, D]
    float* __restrict__ wts)          // [B, T] raw scores in, weights out
{
    const int blk  = blockIdx.x;
    const int b    = blk >> 3;        // / 8
    const int s    = blk & 7;         // % 8
    const int tid  = threadIdx.x;
    const int base = b * NT;          // NT = 64

    __shared__ float sscale[NT];
    __shared__ float sML[2];
    __shared__ float oc_sh[256];

    // ---- wave 0: M and invL via 64-lane butterflies ----
    if (tid < 64) {
        const float mv = part_m[base + tid];
        float M = mv;
        #pragma unroll
        for (int off = 32; off >= 1; off >>= 1)
            M = fmaxf(M, __shfl_xor(M, off, 64));

        const float sc = __expf(mv - M);
        sscale[tid] = sc;

        float lv = part_l[base + tid] * sc;
        #pragma unroll
        for (int off = 32; off >= 1; off >>= 1)
            lv += __shfl_xor(lv, off, 64);

        if (tid == 0) { sML[0] = M; sML[1] = 1.0f / lv; }
    }
    __syncthreads();
    const float M    = sML[0];
    const float invL = sML[1];

    // ---- normalize weights slice s: 256 threads x 1 f4 = 1024 floats ----
    f4* wp = reinterpret_cast<f4*>(wts + (size_t)b * T_) + s * 256 + tid;
    f4 x = *wp;
    x.x = __expf(x.x - M) * invL;
    x.y = __expf(x.y - M) * invL;
    x.z = __expf(x.z - M) * invL;
    x.w = __expf(x.w - M) * invL;
    *wp = x;

    // ---- ctx d-split: blocks s=0,1 each own 128 d-columns ----
    if (s < 2) {
        const int d  = s * 128 + (tid & 127);
        const int ph = tid >> 7;              // 0/1: partials split
        float o = 0.0f;
        #pragma unroll 4
        for (int p = ph * 32; p < ph * 32 + 32; ++p)
            o = fmaf(part_o[(size_t)(base + p) * D_ + d], sscale[p], o);
        oc_sh[tid] = o;
        __syncthreads();
        if (tid < 128)
            ctx[b * D_ + d] = (oc_sh[tid] + oc_sh[tid + 128]) * invL;
    }
}

extern "C" void kernel_launch(void* const* d_in, const int* in_sizes, int n_in,
                              void* d_out, int out_size, void* d_ws, size_t ws_size,
                              hipStream_t stream)
{
    const float* q = (const float*)d_in[0];   // [B, D]
    const float* v = (const float*)d_in[1];   // [B, T, D]

    float* out = (float*)d_out;
    float* ctx = out;             // [B, D]
    float* wts = out + B_ * D_;   // [B, T]

    // workspace: part_m[NPART] | part_l[NPART] | part_o[NPART*D_]
    float* part_m = (float*)d_ws;
    float* part_l = part_m + NPART;
    float* part_o = part_l + NPART;

    attn_pass1<<<NPART, 256, 0, stream>>>(q, v, wts, part_m, part_l, part_o);
    attn_pass2<<<B_ * 8, 256, 0, stream>>>(part_m, part_l, part_o, ctx, wts);
}

// Round 9
// 48.377 us; speedup vs baseline: 1.1068x; 1.0207x over previous
//
#include <hip/hip_runtime.h>
#include <math.h>

// query:  [B, D]   f32
// values: [B, T, D] f32
// out: context [B, D] ++ weights [B, T], f32, concatenated flat.
#define B_ 32
#define T_ 8192
#define D_ 256
#define TTILE 128            // t-rows per block
#define NT (T_ / TTILE)      // 64 tiles per batch
#define NPART (B_ * NT)      // 2048 blocks / partials
#define RESC_THR 8.0f        // defer-max threshold (exp bounded by e^8)

// ---------------------------------------------------------------------------
// Pass 1: stream values ONCE. (Round-3 configuration — measured best 48.4 us;
// R6 occupancy-cap, R7 max-occupancy restructure, R8 wide-pass2 all regressed.)
// Block = (b, tile of 128 rows). 4 waves x 2 half-waves = 8 row-streams.
// Each half-wave (32 lanes x 8 floats) owns one row per iteration.
// Depth-2 prefetch, peeled tail. Online softmax with deferred rescale
// (anchor m, trigger at p > m+8; exp bounded by e^8 — exact after merge).
// pass1 ~44.5 us = ~6.05 TB/s HBM read ≈ 96% of measured streaming ceiling.
// ---------------------------------------------------------------------------
__global__ __launch_bounds__(256) void attn_pass1(
    const float* __restrict__ q,
    const float* __restrict__ v,
    float* __restrict__ scores_out,   // weights region of d_out (raw scores)
    float* __restrict__ part_m,
    float* __restrict__ part_l,
    float* __restrict__ part_o)
{
    const int blk  = blockIdx.x;
    const int b    = blk >> 6;        // / NT
    const int tile = blk & (NT - 1);  // % NT
    const int t0   = tile * TTILE;
    const int tid  = threadIdx.x;
    const int wave = tid >> 6;
    const int lane = tid & 63;
    const int half = lane >> 5;       // 0 or 1
    const int hl   = lane & 31;       // lane within half-wave
    const int sid  = wave * 2 + half; // stream id, 0..7

    __shared__ float s_sh[TTILE];
    __shared__ float sm[8], sl[8];
    __shared__ float so[8][D_];

    // q slice: 8 consecutive floats per lane (32 lanes cover D=256)
    const float4* q4p = reinterpret_cast<const float4*>(q + b * D_);
    const float4 q0 = q4p[hl * 2];
    const float4 q1 = q4p[hl * 2 + 1];

    const float* vbase = v + ((size_t)b * T_ + t0 + sid) * D_;

    float  m = -INFINITY;
    float  l = 0.0f;
    float4 o0 = make_float4(0.f, 0.f, 0.f, 0.f);
    float4 o1 = make_float4(0.f, 0.f, 0.f, 0.f);

    // row loader: iteration i covers row t0 + i*8 + sid
    auto ld = [&](int i, float4& x0, float4& x1) {
        const float4* p =
            reinterpret_cast<const float4*>(vbase + (size_t)i * 8 * D_);
        x0 = p[hl * 2];
        x1 = p[hl * 2 + 1];
    };

    // score + online-softmax update for one row
    auto proc = [&](int i, const float4& a0, const float4& a1) {
        float p = fmaf(q0.x, a0.x, fmaf(q0.y, a0.y,
                  fmaf(q0.z, a0.z, fmaf(q0.w, a0.w,
                  fmaf(q1.x, a1.x, fmaf(q1.y, a1.y,
                  fmaf(q1.z, a1.z, q1.w * a1.w)))))));

        // 5-step butterfly within the 32-lane half
        #pragma unroll
        for (int off = 16; off >= 1; off >>= 1)
            p += __shfl_xor(p, off, 64);

        if (hl == 0) s_sh[i * 8 + sid] = p;   // raw score

        // deferred-rescale online softmax (anchor m)
        if (__any(p > m + RESC_THR)) {
            const float mnew = fmaxf(m, p);
            const float sc   = __expf(m - mnew);   // exp(-inf)=0 first time
            l    *= sc;
            o0.x *= sc; o0.y *= sc; o0.z *= sc; o0.w *= sc;
            o1.x *= sc; o1.y *= sc; o1.z *= sc; o1.w *= sc;
            m = mnew;
        }
        const float w = __expf(p - m);    // bounded by e^RESC_THR
        l += w;
        o0.x = fmaf(w, a0.x, o0.x); o0.y = fmaf(w, a0.y, o0.y);
        o0.z = fmaf(w, a0.z, o0.z); o0.w = fmaf(w, a0.w, o0.w);
        o1.x = fmaf(w, a1.x, o1.x); o1.y = fmaf(w, a1.y, o1.y);
        o1.z = fmaf(w, a1.z, o1.z); o1.w = fmaf(w, a1.w, o1.w);
    };

    float4 A0, A1, B0, B1;
    ld(0, A0, A1);
    ld(1, B0, B1);

    #pragma unroll
    for (int i = 0; i < 16; i += 2) {
        float4 C0, C1, E0, E1;
        if (i + 2 < 16) ld(i + 2, C0, C1);
        if (i + 3 < 16) ld(i + 3, E0, E1);
        proc(i,     A0, A1);
        proc(i + 1, B0, B1);
        if (i + 2 < 16) { A0 = C0; A1 = C1; }
        if (i + 3 < 16) { B0 = E0; B1 = E1; }
    }

    // stash per-stream state
    if (hl == 0) { sm[sid] = m; sl[sid] = l; }
    float4* sop = reinterpret_cast<float4*>(&so[sid][hl * 8]);
    sop[0] = o0;
    sop[1] = o1;
    __syncthreads();

    // combine the 8 streams (every thread recomputes the cheap scalars)
    float M = sm[0];
    #pragma unroll
    for (int s = 1; s < 8; ++s) M = fmaxf(M, sm[s]);

    float es[8];
    #pragma unroll
    for (int s = 0; s < 8; ++s) es[s] = __expf(sm[s] - M);

    float oc = 0.0f;
    #pragma unroll
    for (int s = 0; s < 8; ++s) oc = fmaf(so[s][tid], es[s], oc);
    part_o[(size_t)blk * D_ + tid] = oc;

    if (tid == 0) {
        float L = 0.0f;
        #pragma unroll
        for (int s = 0; s < 8; ++s) L = fmaf(sl[s], es[s], L);
        part_m[blk] = M;
        part_l[blk] = L;
    }

    // coalesced raw-score store
    if (tid < TTILE)
        scores_out[(size_t)b * T_ + t0 + tid] = s_sh[tid];
}

// ---------------------------------------------------------------------------
// Pass 2 (fused): one 1024-thread block per batch b.  (Round-3 proven)
//   wave 0:    butterfly-reduce NT=64 partial (m,l) -> M, invL
//   4 groups:  16 partials each -> ctx (4x parallel reduction)
//   all 1024:  normalize 8192 raw scores (2 x float4 per thread)
// ---------------------------------------------------------------------------
__global__ __launch_bounds__(1024) void attn_pass2(
    const float* __restrict__ part_m,
    const float* __restrict__ part_l,
    const float* __restrict__ part_o,
    float* __restrict__ ctx,          // [B, D]
    float* __restrict__ wts)          // [B, T] raw scores in, weights out
{
    const int b    = blockIdx.x;
    const int tid  = threadIdx.x;
    const int base = b * NT;          // NT = 64

    __shared__ float sscale[NT];
    __shared__ float sML[2];
    __shared__ float octx[4][D_];

    // ---- wave 0: M and invL via 64-lane butterflies ----
    if (tid < 64) {
        const float mv = part_m[base + tid];
        float M = mv;
        #pragma unroll
        for (int off = 32; off >= 1; off >>= 1)
            M = fmaxf(M, __shfl_xor(M, off, 64));

        const float sc = __expf(mv - M);
        sscale[tid] = sc;

        float lv = part_l[base + tid] * sc;
        #pragma unroll
        for (int off = 32; off >= 1; off >>= 1)
            lv += __shfl_xor(lv, off, 64);

        if (tid == 0) { sML[0] = M; sML[1] = 1.0f / lv; }
    }
    __syncthreads();
    const float M    = sML[0];
    const float invL = sML[1];

    // ---- ctx: 4 groups x 16 partials, coalesced over d ----
    const int grp = tid >> 8;   // 0..3
    const int d   = tid & 255;
    float o = 0.0f;
    #pragma unroll
    for (int p = 0; p < 16; ++p) {
        const int pi = grp * 16 + p;
        o = fmaf(part_o[(size_t)(base + pi) * D_ + d], sscale[pi], o);
    }
    octx[grp][d] = o;
    __syncthreads();
    if (tid < D_)
        ctx[b * D_ + tid] =
            (octx[0][tid] + octx[1][tid] + octx[2][tid] + octx[3][tid]) * invL;

    // ---- normalize weights: 1024 threads x float4 x 2 ----
    float4* wp = reinterpret_cast<float4*>(wts + (size_t)b * T_);
    #pragma unroll
    for (int it = 0; it < 2; ++it) {
        float4 x = wp[it * 1024 + tid];
        x.x = __expf(x.x - M) * invL;
        x.y = __expf(x.y - M) * invL;
        x.z = __expf(x.z - M) * invL;
        x.w = __expf(x.w - M) * invL;
        wp[it * 1024 + tid] = x;
    }
}

extern "C" void kernel_launch(void* const* d_in, const int* in_sizes, int n_in,
                              void* d_out, int out_size, void* d_ws, size_t ws_size,
                              hipStream_t stream)
{
    const float* q = (const float*)d_in[0];   // [B, D]
    const float* v = (const float*)d_in[1];   // [B, T, D]

    float* out = (float*)d_out;
    float* ctx = out;             // [B, D]
    float* wts = out + B_ * D_;   // [B, T]

    // workspace: part_m[NPART] | part_l[NPART] | part_o[NPART*D_]
    float* part_m = (float*)d_ws;
    float* part_l = part_m + NPART;
    float* part_o = part_l + NPART;

    attn_pass1<<<NPART, 256, 0, stream>>>(q, v, wts, part_m, part_l, part_o);
    attn_pass2<<<B_, 1024, 0, stream>>>(part_m, part_l, part_o, ctx, wts);
}